// Round 1
// baseline (442.631 us; speedup 1.0000x reference)
//
#include <hip/hip_runtime.h>
#include <hip/hip_bf16.h>
#include <math.h>

#define B_    8
#define C_    256
#define L_    4096
#define OCH_  256
#define K_    3
#define OG_   4
#define HID_  64
#define TL    32          // l-tile per conv block

// ---------------------------------------------------------------------------
// K0: transpose weight (O,C,K) -> Wt[c][o][k]  (so conv loads are coalesced)
// ---------------------------------------------------------------------------
__global__ void k_transpose(const float* __restrict__ W, float* __restrict__ Wt) {
    int idx = blockIdx.x * 256 + threadIdx.x;        // over O*C*K = 196608
    if (idx >= OCH_ * C_ * K_) return;
    int k = idx % K_;
    int c = (idx / K_) % C_;
    int o = idx / (K_ * C_);
    Wt[(c * OCH_ + o) * K_ + k] = W[idx];
}

// ---------------------------------------------------------------------------
// K1: offset network. One thread per (b,l).
// Emits per (b,k,l): float4 { c0*mod, c1*mod, bits(i0_clamped), bits(i1_clamped) }
// ---------------------------------------------------------------------------
__global__ __launch_bounds__(256) void k_offsets(
        const float* __restrict__ x,
        const float* __restrict__ w1, const float* __restrict__ b1,
        const float* __restrict__ w2, const float* __restrict__ b2,
        float4* __restrict__ coef) {
    int pos = blockIdx.x * 256 + threadIdx.x;        // B*L threads
    int b = pos >> 12;                               // L = 4096
    int l = pos & (L_ - 1);
    const float* xb = x + (size_t)b * C_ * L_ + l;

    float om[OG_ * 9];
    #pragma unroll
    for (int j = 0; j < OG_ * 9; ++j) om[j] = b2[j];

    for (int g = 0; g < OG_; ++g) {
        float xv[64];
        #pragma unroll
        for (int c = 0; c < 64; ++c) xv[c] = xb[(size_t)(g * 64 + c) * L_];
        #pragma unroll
        for (int o = 0; o < 16; ++o) {
            float a = b1[g * 16 + o];
            const float* w1p = w1 + (g * 16 + o) * 64;
            #pragma unroll
            for (int c = 0; c < 64; ++c) a = fmaf(xv[c], w1p[c], a);
            // exact GELU: 0.5*a*(1+erf(a/sqrt(2)))
            float hv = 0.5f * a * (1.0f + erff(a * 0.70710678118654752f));
            const float* w2p = w2 + g * 9 * 16 + o;
            #pragma unroll
            for (int o2 = 0; o2 < 9; ++o2)
                om[g * 9 + o2] = fmaf(hv, w2p[o2 * 16], om[g * 9 + o2]);
        }
    }

    // zero channels 1,3,5 (om[:,1:6:2,:] = 0)
    om[1] = 0.0f; om[3] = 0.0f; om[5] = 0.0f;

    // softmax over channels 3..35, keep first 3 (= channels 3,4,5)
    float m = om[3];
    #pragma unroll
    for (int j = 4; j < 36; ++j) m = fmaxf(m, om[j]);
    float ssum = 0.0f;
    #pragma unroll
    for (int j = 3; j < 36; ++j) ssum += expf(om[j] - m);
    float inv = 1.0f / ssum;

    float base = -1.0f + 2.0f * (float)l / (float)(L_ - 1);
    #pragma unroll
    for (int k = 0; k < K_; ++k) {
        float mod = expf(om[3 + k] - m) * inv;
        float off = om[2 * k] * (2.0f / (float)L_);
        float grid = base + (-0.5f + 0.5f * (float)k) + off;
        float p = (grid + 1.0f) * 0.5f * (float)(L_ - 1);
        float fp = floorf(p);
        int i0 = (int)fp;
        int i1 = i0 + 1;
        float w = p - fp;
        float v0 = (i0 >= 0 && i0 < L_) ? 1.0f : 0.0f;
        float v1 = (i1 >= 0 && i1 < L_) ? 1.0f : 0.0f;
        int i0c = min(max(i0, 0), L_ - 1);
        int i1c = min(max(i1, 0), L_ - 1);
        float c0 = (1.0f - w) * v0 * mod;
        float c1 = w * v1 * mod;
        coef[((size_t)b * K_ + k) * L_ + l] =
            make_float4(c0, c1, __int_as_float(i0c), __int_as_float(i1c));
    }
}

// ---------------------------------------------------------------------------
// K2: main conv. Block = 256 threads (one per output channel o), TL l's.
// Stage sampled matrix s[c][k][l] (768 x TL) in LDS, then dense FMA loop.
// ---------------------------------------------------------------------------
__global__ __launch_bounds__(256) void k_conv(
        const float* __restrict__ x,
        const float* __restrict__ Wt, const float* __restrict__ bias,
        const float4* __restrict__ coef, float* __restrict__ out) {
    __shared__ float s[C_ * K_ * TL];                // 96 KB
    int blk = blockIdx.x;
    int b  = blk >> 7;                               // L_/TL = 128 tiles per b
    int l0 = (blk & 127) * TL;
    int tid  = threadIdx.x;
    int lsub = tid & 31;
    int csub = tid >> 5;                             // 8 channel sub-groups
    const float* xb = x + (size_t)b * C_ * L_;

    #pragma unroll
    for (int k = 0; k < K_; ++k) {
        float4 cf = coef[((size_t)b * K_ + k) * L_ + l0 + lsub];
        int i0 = __float_as_int(cf.z), i1 = __float_as_int(cf.w);
        #pragma unroll 4
        for (int co = 0; co < 32; ++co) {
            int c = co * 8 + csub;
            const float* xc = xb + (size_t)c * L_;
            s[(c * K_ + k) * TL + lsub] = xc[i0] * cf.x + xc[i1] * cf.y;
        }
    }
    __syncthreads();

    int o = tid;
    float acc[TL];
    float bv = bias[o];
    #pragma unroll
    for (int l = 0; l < TL; ++l) acc[l] = bv;

    const float* wp = Wt + o * K_;                   // Wt[c*768 + o*3 + k]
    for (int c = 0; c < C_; ++c) {
        float w0 = wp[c * (OCH_ * K_) + 0];
        float w1 = wp[c * (OCH_ * K_) + 1];
        float w2 = wp[c * (OCH_ * K_) + 2];
        const float* sp = s + c * K_ * TL;
        #pragma unroll
        for (int l = 0; l < TL; ++l) acc[l] = fmaf(sp[l], w0, acc[l]);
        #pragma unroll
        for (int l = 0; l < TL; ++l) acc[l] = fmaf(sp[TL + l], w1, acc[l]);
        #pragma unroll
        for (int l = 0; l < TL; ++l) acc[l] = fmaf(sp[2 * TL + l], w2, acc[l]);
    }

    float* op = out + ((size_t)b * OCH_ + o) * L_ + l0;
    #pragma unroll
    for (int l = 0; l < TL; ++l) op[l] = acc[l];
}

// ---------------------------------------------------------------------------
extern "C" void kernel_launch(void* const* d_in, const int* in_sizes, int n_in,
                              void* d_out, int out_size, void* d_ws, size_t ws_size,
                              hipStream_t stream) {
    const float* x      = (const float*)d_in[0];
    const float* weight = (const float*)d_in[1];
    const float* bias   = (const float*)d_in[2];
    const float* w1     = (const float*)d_in[3];
    const float* b1     = (const float*)d_in[4];
    const float* w2     = (const float*)d_in[5];
    const float* b2     = (const float*)d_in[6];
    float* out = (float*)d_out;

    char* ws = (char*)d_ws;
    float4* coef = (float4*)ws;                                    // B*3*L*16 = 1.5 MB
    float*  Wt   = (float*)(ws + (size_t)B_ * K_ * L_ * sizeof(float4)); // 768 KB

    k_transpose<<<(OCH_ * C_ * K_ + 255) / 256, 256, 0, stream>>>(weight, Wt);
    k_offsets<<<B_ * L_ / 256, 256, 0, stream>>>(x, w1, b1, w2, b2, coef);
    k_conv<<<B_ * (L_ / TL), 256, 0, stream>>>(x, Wt, bias, coef, out);
}

// Round 2
// 283.448 us; speedup vs baseline: 1.5616x; 1.5616x over previous
//
#include <hip/hip_runtime.h>
#include <hip/hip_bf16.h>
#include <math.h>

#define B_    8
#define C_    256
#define L_    4096
#define OCH_  256
#define K_    3
#define OG_   4
#define HID_  64

#define BO 64            // o-tile per block
#define BL 128           // l-tile per block
#define CC 16            // c-chunk staged per barrier
#define ROWS (CC*K_)     // 48
#define NCH (C_/CC)      // 16

// ---------------------------------------------------------------------------
// K0: transpose weight (O,C,K) -> Wt2[c][k][o]  (o contiguous: coalesced stage)
// ---------------------------------------------------------------------------
__global__ void k_transpose(const float* __restrict__ W, float* __restrict__ Wt2) {
    int idx = blockIdx.x * 256 + threadIdx.x;        // ((c*3+k)*256 + o)
    if (idx >= OCH_ * C_ * K_) return;
    int o  = idx & 255;
    int ck = idx >> 8;
    int c = ck / 3, k = ck - 3 * c;
    Wt2[idx] = W[(o * C_ + c) * K_ + k];
}

// ---------------------------------------------------------------------------
// K1: offset network, 4 threads per (b,l) (one per group), LDS combine.
// Emits per (b,k,l): float4 { c0*mod, c1*mod, bits(i0c), bits(i1c) }
// ---------------------------------------------------------------------------
__global__ __launch_bounds__(256) void k_offsets(
        const float* __restrict__ x,
        const float* __restrict__ w1, const float* __restrict__ b1,
        const float* __restrict__ w2, const float* __restrict__ b2,
        float4* __restrict__ coef) {
    __shared__ float sOm[64][36];
    int tid = threadIdx.x;
    int p = tid >> 2;                                // local position 0..63
    int g = tid & 3;                                 // group
    int pos = blockIdx.x * 64 + p;
    int b = pos >> 12;                               // L = 4096
    int l = pos & (L_ - 1);
    const float* xb = x + (size_t)b * C_ * L_ + l;

    float om9[9];
    #pragma unroll
    for (int j = 0; j < 9; ++j) om9[j] = b2[g * 9 + j];

    float xv[64];
    #pragma unroll
    for (int c = 0; c < 64; ++c) xv[c] = xb[(size_t)(g * 64 + c) * L_];
    #pragma unroll
    for (int o = 0; o < 16; ++o) {
        float a = b1[g * 16 + o];
        const float* w1p = w1 + (g * 16 + o) * 64;
        #pragma unroll
        for (int c = 0; c < 64; ++c) a = fmaf(xv[c], w1p[c], a);
        float hv = 0.5f * a * (1.0f + erff(a * 0.70710678118654752f));
        const float* w2p = w2 + g * 144 + o;         // w2[g][j][o], 9x16 per g
        #pragma unroll
        for (int j = 0; j < 9; ++j) om9[j] = fmaf(hv, w2p[j * 16], om9[j]);
    }
    #pragma unroll
    for (int j = 0; j < 9; ++j) sOm[p][g * 9 + j] = om9[j];
    __syncthreads();
    if (g != 0) return;

    float om[36];
    #pragma unroll
    for (int j = 0; j < 36; ++j) om[j] = sOm[p][j];
    om[1] = 0.0f; om[3] = 0.0f; om[5] = 0.0f;

    float m = om[3];
    #pragma unroll
    for (int j = 4; j < 36; ++j) m = fmaxf(m, om[j]);
    float ssum = 0.0f;
    #pragma unroll
    for (int j = 3; j < 36; ++j) ssum += expf(om[j] - m);
    float inv = 1.0f / ssum;

    float base = -1.0f + 2.0f * (float)l / (float)(L_ - 1);
    #pragma unroll
    for (int k = 0; k < K_; ++k) {
        float mod = expf(om[3 + k] - m) * inv;
        float off = om[2 * k] * (2.0f / (float)L_);
        float grid = base + (-0.5f + 0.5f * (float)k) + off;
        float pp = (grid + 1.0f) * 0.5f * (float)(L_ - 1);
        float fp = floorf(pp);
        int i0 = (int)fp;
        int i1 = i0 + 1;
        float w = pp - fp;
        float v0 = (i0 >= 0 && i0 < L_) ? 1.0f : 0.0f;
        float v1 = (i1 >= 0 && i1 < L_) ? 1.0f : 0.0f;
        int i0c = min(max(i0, 0), L_ - 1);
        int i1c = min(max(i1, 0), L_ - 1);
        coef[((size_t)b * K_ + k) * L_ + l] =
            make_float4((1.0f - w) * v0 * mod, w * v1 * mod,
                        __int_as_float(i0c), __int_as_float(i1c));
    }
}

// ---------------------------------------------------------------------------
// K2: main conv. Block 256 threads -> 64o x 128l tile, 4o x 8l per thread.
// c chunked by 16; sS[48][128] sampled + sW[48][64] weights in LDS (36 KB).
// ---------------------------------------------------------------------------
__global__ __launch_bounds__(256, 4) void k_conv(
        const float* __restrict__ x, const float* __restrict__ Wt2,
        const float* __restrict__ bias, const float4* __restrict__ coef,
        float* __restrict__ out) {
    __shared__ float  sS[ROWS][BL];                  // 24 KB
    __shared__ float4 sW4[ROWS * (BO / 4)];          // 12 KB  ([48][64] floats)

    int bid = blockIdx.x;
    int otile = bid & 3;
    int ltile = (bid >> 2) & 31;
    int b = bid >> 7;
    int l0 = ltile * BL;
    int o0 = otile * BO;
    int tid = threadIdx.x;
    int lg = tid & 15, og = tid >> 4;                // compute mapping
    int grp = tid >> 7, lsub = tid & 127;            // staging mapping
    const float* xb = x + (size_t)b * C_ * L_;

    // per-thread sampling coefficients for column l0+lsub
    int i0a[3], i1a[3]; float c0a[3], c1a[3];
    #pragma unroll
    for (int k = 0; k < 3; ++k) {
        float4 cf = coef[((size_t)b * 3 + k) * L_ + l0 + lsub];
        c0a[k] = cf.x; c1a[k] = cf.y;
        i0a[k] = __float_as_int(cf.z); i1a[k] = __float_as_int(cf.w);
    }

    float acc[4][8];
    #pragma unroll
    for (int oi = 0; oi < 4; ++oi) {
        float bv = bias[o0 + og * 4 + oi];
        #pragma unroll
        for (int li = 0; li < 8; ++li) acc[oi][li] = bv;
    }

    const float4* Wt2f4 = (const float4*)Wt2;        // row = 64 f4 (256 o)

    for (int ch = 0; ch < NCH; ++ch) {
        if (ch) __syncthreads();
        // ---- stage sampled values: 8 channels per staging group ----
        int cbase = ch * CC + grp * 8;
        #pragma unroll
        for (int ci = 0; ci < 8; ++ci) {
            const float* xc = xb + (size_t)(cbase + ci) * L_;
            int r = (grp * 8 + ci) * 3;
            #pragma unroll
            for (int k = 0; k < 3; ++k)
                sS[r + k][lsub] = xc[i0a[k]] * c0a[k] + xc[i1a[k]] * c1a[k];
        }
        // ---- stage weights: 48 rows x 16 f4, fully coalesced ----
        #pragma unroll
        for (int j = 0; j < 3; ++j) {
            int flat = j * 256 + tid;                // 0..767
            int row = flat >> 4, of4 = flat & 15;
            sW4[flat] = Wt2f4[(size_t)(ch * ROWS + row) * (OCH_ / 4) + otile * 16 + of4];
        }
        __syncthreads();
        // ---- compute ----
        for (int ci = 0; ci < CC; ++ci) {
            int r = ci * 3;
            float4 w0 = sW4[(r + 0) * 16 + og];
            float4 w1 = sW4[(r + 1) * 16 + og];
            float4 w2 = sW4[(r + 2) * 16 + og];
            const float* wv0 = (const float*)&w0;
            const float* wv1 = (const float*)&w1;
            const float* wv2 = (const float*)&w2;
            float s0[8], s1[8], s2[8];
            #pragma unroll
            for (int li = 0; li < 8; ++li) s0[li] = sS[r + 0][lg + 16 * li];
            #pragma unroll
            for (int li = 0; li < 8; ++li) s1[li] = sS[r + 1][lg + 16 * li];
            #pragma unroll
            for (int li = 0; li < 8; ++li) s2[li] = sS[r + 2][lg + 16 * li];
            #pragma unroll
            for (int oi = 0; oi < 4; ++oi) {
                #pragma unroll
                for (int li = 0; li < 8; ++li) {
                    float a = acc[oi][li];
                    a = fmaf(s0[li], wv0[oi], a);
                    a = fmaf(s1[li], wv1[oi], a);
                    a = fmaf(s2[li], wv2[oi], a);
                    acc[oi][li] = a;
                }
            }
        }
    }

    float* op = out + ((size_t)b * OCH_ + o0 + og * 4) * L_ + l0 + lg;
    #pragma unroll
    for (int oi = 0; oi < 4; ++oi)
        #pragma unroll
        for (int li = 0; li < 8; ++li)
            op[(size_t)oi * L_ + 16 * li] = acc[oi][li];
}

// ---------------------------------------------------------------------------
extern "C" void kernel_launch(void* const* d_in, const int* in_sizes, int n_in,
                              void* d_out, int out_size, void* d_ws, size_t ws_size,
                              hipStream_t stream) {
    const float* x      = (const float*)d_in[0];
    const float* weight = (const float*)d_in[1];
    const float* bias   = (const float*)d_in[2];
    const float* w1     = (const float*)d_in[3];
    const float* b1     = (const float*)d_in[4];
    const float* w2     = (const float*)d_in[5];
    const float* b2     = (const float*)d_in[6];
    float* out = (float*)d_out;

    char* ws = (char*)d_ws;
    float4* coef = (float4*)ws;                                        // 1.5 MB
    float*  Wt2  = (float*)(ws + (size_t)B_ * K_ * L_ * sizeof(float4)); // 768 KB

    k_transpose<<<(OCH_ * C_ * K_ + 255) / 256, 256, 0, stream>>>(weight, Wt2);
    k_offsets<<<(B_ * L_) / 64, 256, 0, stream>>>(x, w1, b1, w2, b2, coef);
    k_conv<<<B_ * (OCH_ / BO) * (L_ / BL), 256, 0, stream>>>(x, Wt2, bias, coef, out);
}

// Round 3
// 97.887 us; speedup vs baseline: 4.5219x; 2.8957x over previous
//
#include <hip/hip_runtime.h>
#include <hip/hip_bf16.h>
#include <math.h>

#define B_    8
#define C_    256
#define L_    4096
#define OCH_  256
#define K_    3
#define OG_   4
#define HID_  64

typedef __attribute__((ext_vector_type(8))) short bf16x8;
typedef __attribute__((ext_vector_type(4))) float f32x4;
typedef __attribute__((ext_vector_type(4))) int   i32x4;

static __device__ __forceinline__ unsigned short f32_to_bf16_rne(float f) {
    unsigned u = __float_as_uint(f);
    unsigned r = u + 0x7FFFu + ((u >> 16) & 1u);
    return (unsigned short)(r >> 16);
}
static __device__ __forceinline__ float bf16_bits_to_f32(unsigned short b) {
    return __uint_as_float((unsigned)b << 16);
}

// ---------------------------------------------------------------------------
// K0: split weights into bf16 hi/lo with K-dim reordered k-major:
//     Whi[o][kk] where kk = k*256 + c   (from W[o][c][k])
// ---------------------------------------------------------------------------
__global__ void k_split(const float* __restrict__ W,
                        unsigned short* __restrict__ Whi,
                        unsigned short* __restrict__ Wlo) {
    int i = blockIdx.x * 256 + threadIdx.x;          // o*768 + c*3 + k
    if (i >= OCH_ * C_ * K_) return;
    int k = i % 3;
    int c = (i / 3) & 255;
    int o = i / 768;
    float w = W[i];
    unsigned short hb = f32_to_bf16_rne(w);
    unsigned short lb = f32_to_bf16_rne(w - bf16_bits_to_f32(hb));
    int dst = o * 768 + k * 256 + c;
    Whi[dst] = hb;
    Wlo[dst] = lb;
}

// ---------------------------------------------------------------------------
// K1: offset network. Block = 256 threads = 4 waves; wave g handles group g
// (block-diagonal in both layers). lane = local l. Wave 0 finishes softmax.
// coef[(b*3+k)*L + l] = { c0*mod, c1*mod, bits(i0c), bits(i1c) }
// ---------------------------------------------------------------------------
__global__ __launch_bounds__(256) void k_offsets(
        const float* __restrict__ x,
        const float* __restrict__ w1, const float* __restrict__ b1,
        const float* __restrict__ w2, const float* __restrict__ b2,
        float4* __restrict__ coef) {
    __shared__ float sOm[64][37];
    int tid  = threadIdx.x;
    int lane = tid & 63;
    int g    = tid >> 6;
    int blk  = blockIdx.x;
    int b    = blk >> 6;
    int l0   = (blk & 63) << 6;
    int l    = l0 + lane;

    const float* xg = x + (size_t)b * C_ * L_ + (size_t)(g * 64) * L_ + l;

    float h[16];
    #pragma unroll
    for (int o = 0; o < 16; ++o) h[o] = b1[g * 16 + o];
    #pragma unroll 4
    for (int cg = 0; cg < 64; ++cg) {
        float xv = xg[(size_t)cg * L_];
        const float* w1p = w1 + (g * 16) * 64 + cg;
        #pragma unroll
        for (int o = 0; o < 16; ++o) h[o] = fmaf(xv, w1p[o * 64], h[o]);
    }

    float om9[9];
    #pragma unroll
    for (int j = 0; j < 9; ++j) om9[j] = b2[g * 9 + j];
    #pragma unroll
    for (int o = 0; o < 16; ++o) {
        float a  = h[o];
        float hv = 0.5f * a * (1.0f + erff(a * 0.70710678118654752f));
        const float* w2p = w2 + g * 144 + o;         // w2[g][j][o]
        #pragma unroll
        for (int j = 0; j < 9; ++j) om9[j] = fmaf(hv, w2p[j * 16], om9[j]);
    }
    #pragma unroll
    for (int j = 0; j < 9; ++j) sOm[lane][g * 9 + j] = om9[j];
    __syncthreads();
    if (g != 0) return;

    float om[36];
    #pragma unroll
    for (int j = 0; j < 36; ++j) om[j] = sOm[lane][j];
    om[1] = 0.0f; om[3] = 0.0f; om[5] = 0.0f;

    float m = om[3];
    #pragma unroll
    for (int j = 4; j < 36; ++j) m = fmaxf(m, om[j]);
    float ssum = 0.0f;
    #pragma unroll
    for (int j = 3; j < 36; ++j) ssum += expf(om[j] - m);
    float inv = 1.0f / ssum;

    float base = -1.0f + 2.0f * (float)l / (float)(L_ - 1);
    #pragma unroll
    for (int kk = 0; kk < K_; ++kk) {
        float mod  = expf(om[3 + kk] - m) * inv;
        float off  = om[2 * kk] * (2.0f / (float)L_);
        float grid = base + (-0.5f + 0.5f * (float)kk) + off;
        float pp   = (grid + 1.0f) * 0.5f * (float)(L_ - 1);
        float fp   = floorf(pp);
        int i0 = (int)fp;
        int i1 = i0 + 1;
        float w = pp - fp;
        float v0 = (i0 >= 0 && i0 < L_) ? 1.0f : 0.0f;
        float v1 = (i1 >= 0 && i1 < L_) ? 1.0f : 0.0f;
        int i0c = min(max(i0, 0), L_ - 1);
        int i1c = min(max(i1, 0), L_ - 1);
        coef[((size_t)b * K_ + kk) * L_ + l] =
            make_float4((1.0f - w) * v0 * mod, w * v1 * mod,
                        __int_as_float(i0c), __int_as_float(i1c));
    }
}

// ---------------------------------------------------------------------------
// K2: fused sample + split-precision MFMA GEMM.
// Block 512 thr (8 waves) -> 256o x 64l. Wave wv owns o-slice wv*32..+32.
// K = 768 (k-major: kk = k*256+c), chunked by 128 (6 chunks, 4 MFMA K-steps).
// LDS: S[l][kslot] bf16 hi/lo, 16B slots XOR-swizzled by (l&7).
// acc = Whi*Shi + Whi*Slo + Wlo*Shi  (3 MFMAs per fragment pair)
// ---------------------------------------------------------------------------
__global__ __launch_bounds__(512, 4) void k_conv(
        const float* __restrict__ x,
        const unsigned short* __restrict__ Whi,
        const unsigned short* __restrict__ Wlo,
        const float* __restrict__ bias,
        const float4* __restrict__ coef,
        float* __restrict__ out) {
    __shared__ i32x4 sHi[64 * 16];                   // 16 KB  [l][slot]
    __shared__ i32x4 sLo[64 * 16];                   // 16 KB

    int tid  = threadIdx.x;
    int blk  = blockIdx.x;
    int b    = blk >> 6;
    int l0   = (blk & 63) * 64;
    int lane = tid & 63;
    int wv   = tid >> 6;                             // wave id 0..7 (= stage row-group)

    const float* xb = x + (size_t)b * (C_ * L_);

    // sampling coefficients for column l0+lane (one per tap)
    int i0a[3], i1a[3]; float c0a[3], c1a[3];
    #pragma unroll
    for (int kk = 0; kk < 3; ++kk) {
        float4 cf = coef[((size_t)b * 3 + kk) * L_ + l0 + lane];
        c0a[kk] = cf.x; c1a[kk] = cf.y;
        i0a[kk] = __float_as_int(cf.z); i1a[kk] = __float_as_int(cf.w);
    }

    f32x4 acc[2][4];                                 // [m][nf]
    #pragma unroll
    for (int m = 0; m < 2; ++m)
        #pragma unroll
        for (int nf = 0; nf < 4; ++nf)
            acc[m][nf] = (f32x4){0.f, 0.f, 0.f, 0.f};

    for (int ch = 0; ch < 6; ++ch) {
        // ---- sample 16 K-rows (fixed tap, 16 consecutive c) for column lane ----
        int rbase = ch * 128 + wv * 16;              // global K-row base
        int tap   = rbase >> 8;                      // uniform across j
        int i0 = i0a[tap], i1 = i1a[tap];
        float c0 = c0a[tap], c1 = c1a[tap];
        const float* xc = xb + (size_t)(rbase & 255) * L_;
        union { unsigned short us[8]; i32x4 v; } ph0, ph1, pl0, pl1;
        #pragma unroll
        for (int j = 0; j < 8; ++j) {
            float s = xc[i0] * c0 + xc[i1] * c1;
            unsigned short hb = f32_to_bf16_rne(s);
            ph0.us[j] = hb;
            pl0.us[j] = f32_to_bf16_rne(s - bf16_bits_to_f32(hb));
            xc += L_;
        }
        #pragma unroll
        for (int j = 0; j < 8; ++j) {
            float s = xc[i0] * c0 + xc[i1] * c1;
            unsigned short hb = f32_to_bf16_rne(s);
            ph1.us[j] = hb;
            pl1.us[j] = f32_to_bf16_rne(s - bf16_bits_to_f32(hb));
            xc += L_;
        }
        __syncthreads();                             // prev chunk consumed
        int s0 = wv * 2;
        int swz = lane & 7;
        sHi[lane * 16 + ((s0 + 0) ^ swz)] = ph0.v;
        sHi[lane * 16 + ((s0 + 1) ^ swz)] = ph1.v;
        sLo[lane * 16 + ((s0 + 0) ^ swz)] = pl0.v;
        sLo[lane * 16 + ((s0 + 1) ^ swz)] = pl1.v;
        __syncthreads();                             // tile ready

        // ---- MFMA over 4 K-steps of 32 ----
        #pragma unroll
        for (int ks = 0; ks < 4; ++ks) {
            int kkg = ch * 128 + ks * 32 + ((lane >> 4) * 8);   // global k for A frag
            bf16x8 ahi[2], alo[2];
            #pragma unroll
            for (int m = 0; m < 2; ++m) {
                int o = wv * 32 + m * 16 + (lane & 15);
                ahi[m] = *(const bf16x8*)(Whi + (size_t)o * 768 + kkg);
                alo[m] = *(const bf16x8*)(Wlo + (size_t)o * 768 + kkg);
            }
            #pragma unroll
            for (int nf = 0; nf < 4; ++nf) {
                int lcol = nf * 16 + (lane & 15);
                int slot = (ks * 4 + (lane >> 4)) ^ (lcol & 7);
                bf16x8 bhi = *(const bf16x8*)&sHi[lcol * 16 + slot];
                bf16x8 blo = *(const bf16x8*)&sLo[lcol * 16 + slot];
                #pragma unroll
                for (int m = 0; m < 2; ++m) {
                    acc[m][nf] = __builtin_amdgcn_mfma_f32_16x16x32_bf16(ahi[m], bhi, acc[m][nf], 0, 0, 0);
                    acc[m][nf] = __builtin_amdgcn_mfma_f32_16x16x32_bf16(ahi[m], blo, acc[m][nf], 0, 0, 0);
                    acc[m][nf] = __builtin_amdgcn_mfma_f32_16x16x32_bf16(alo[m], bhi, acc[m][nf], 0, 0, 0);
                }
            }
        }
    }

    // ---- epilogue: add bias, store. D: row(o) = (lane>>4)*4+reg, col(l) = lane&15
    #pragma unroll
    for (int m = 0; m < 2; ++m) {
        #pragma unroll
        for (int reg = 0; reg < 4; ++reg) {
            int o = wv * 32 + m * 16 + (lane >> 4) * 4 + reg;
            float bv = bias[o];
            float* op = out + ((size_t)(b * 256 + o)) * L_ + l0 + (lane & 15);
            #pragma unroll
            for (int nf = 0; nf < 4; ++nf)
                op[nf * 16] = acc[m][nf][reg] + bv;
        }
    }
}

// ---------------------------------------------------------------------------
extern "C" void kernel_launch(void* const* d_in, const int* in_sizes, int n_in,
                              void* d_out, int out_size, void* d_ws, size_t ws_size,
                              hipStream_t stream) {
    const float* x      = (const float*)d_in[0];
    const float* weight = (const float*)d_in[1];
    const float* bias   = (const float*)d_in[2];
    const float* w1     = (const float*)d_in[3];
    const float* b1     = (const float*)d_in[4];
    const float* w2     = (const float*)d_in[5];
    const float* b2     = (const float*)d_in[6];
    float* out = (float*)d_out;

    char* ws = (char*)d_ws;
    float4* coef = (float4*)ws;                                   // 1.5 MB
    unsigned short* Whi = (unsigned short*)(ws + (size_t)B_ * K_ * L_ * sizeof(float4));
    unsigned short* Wlo = Whi + OCH_ * C_ * K_;                   // +384 KB each

    k_split<<<(OCH_ * C_ * K_ + 255) / 256, 256, 0, stream>>>(weight, Whi, Wlo);
    k_offsets<<<(B_ * L_) / 64, 256, 0, stream>>>(x, w1, b1, w2, b2, coef);
    k_conv<<<B_ * (L_ / 64), 512, 0, stream>>>(x, Whi, Wlo, bias, coef, out);
}